// Round 6
// baseline (255.694 us; speedup 1.0000x reference)
//
#include <hip/hip_runtime.h>
#include <hip/hip_fp16.h>
#include <math.h>

#define C 128
#define BSHIFT 9        // bucket width = 512 nodes
#define BWIDTH 512
#define NBMAX 256       // >= ceil(100000/512)=196
#define COLBITS 17      // N=100000 < 2^17; ebuf packs (lrow<<17)|col
#define NSLICE 8        // feature slices: 16 ch x 2B = 32B/row; 3.2MB/slice < 4MB XCD-L2

typedef _Float16 v8hf __attribute__((ext_vector_type(8)));
typedef float v4f __attribute__((ext_vector_type(4)));

// ---- 1. bucket histogram: bcount[row>>9] += 1 (LDS-aggregated) ----
__global__ __launch_bounds__(256) void bucket_hist_kernel(const int4* __restrict__ rowI4,
                                                          const int* __restrict__ rowI,
                                                          int* __restrict__ bcount,
                                                          int E4, int E, int NB) {
    __shared__ int h[NBMAX];
    int t = threadIdx.x;
    h[t] = 0;
    __syncthreads();
    for (int i = blockIdx.x * 256 + t; i < E4; i += gridDim.x * 256) {
        int4 r = rowI4[i];
        atomicAdd(&h[r.x >> BSHIFT], 1);
        atomicAdd(&h[r.y >> BSHIFT], 1);
        atomicAdd(&h[r.z >> BSHIFT], 1);
        atomicAdd(&h[r.w >> BSHIFT], 1);
    }
    if (blockIdx.x == 0 && t == 0) {          // tail (E not multiple of 4)
        for (int e = E4 * 4; e < E; ++e) atomicAdd(&h[rowI[e] >> BSHIFT], 1);
    }
    __syncthreads();
    if (t < NB && h[t]) atomicAdd(&bcount[t], h[t]);
}

// ---- 2. bucket scan: parallel LDS scan (NB <= 256) ----
__global__ __launch_bounds__(256) void bucket_scan_kernel(const int* __restrict__ bcount,
                                                          int* __restrict__ bstart,
                                                          int* __restrict__ gcur, int NB) {
    __shared__ int sc[256];
    int t = threadIdx.x;
    int v = (t < NB) ? bcount[t] : 0;
    sc[t] = v;
    __syncthreads();
    for (int o = 1; o < 256; o <<= 1) {       // Hillis-Steele inclusive
        int u = (t >= o) ? sc[t - o] : 0;
        __syncthreads();
        sc[t] += u;
        __syncthreads();
    }
    int excl = sc[t] - v;
    if (t < NB) { bstart[t] = excl; gcur[t] = excl; }
    if (t == 255) bstart[NB] = sc[255];
}

// ---- 3. scatter edges into bucket-ordered ebuf, packed (lrow<<17)|col ----
__global__ __launch_bounds__(256) void p2_scatter_kernel(const int* __restrict__ rowI,
                                                         const int* __restrict__ colI,
                                                         int* __restrict__ gcur,
                                                         unsigned* __restrict__ ebuf, int E) {
    __shared__ int cnt[NBMAX];
    __shared__ int base[NBMAX];
    const int t = threadIdx.x;
    cnt[t] = 0;
    __syncthreads();
    const int chunk = blockIdx.x * 4096;
    int ranks[16];
#pragma unroll
    for (int k = 0; k < 16; ++k) {
        int e = chunk + k * 256 + t;
        if (e < E) {
            int r = rowI[e];
            ranks[k] = atomicAdd(&cnt[r >> BSHIFT], 1);
        }
    }
    __syncthreads();
    {
        int c = cnt[t];
        base[t] = c ? atomicAdd(&gcur[t], c) : 0;
    }
    __syncthreads();
#pragma unroll
    for (int k = 0; k < 16; ++k) {
        int e = chunk + k * 256 + t;
        if (e < E) {
            int r = rowI[e];           // L1-hot re-read
            unsigned c = (unsigned)colI[e];
            unsigned packed = ((unsigned)(r & (BWIDTH - 1)) << COLBITS) | c;
            ebuf[base[r >> BSHIFT] + ranks[k]] = packed;
        }
    }
}

// ---- 4. per-bucket place: LDS count + scan + LDS-cursor placement ----
// Emits offs_end[node], inv[node] = rsqrt(deg+1), csr (cols only).
__global__ __launch_bounds__(512) void p3_place_kernel(const unsigned* __restrict__ ebuf,
                                                       const int* __restrict__ bstart,
                                                       int* __restrict__ offs_end,
                                                       float* __restrict__ inv,
                                                       int* __restrict__ csr, int N) {
    __shared__ int cnt[BWIDTH];
    __shared__ int sc[BWIDTH];
    const int b = blockIdx.x;
    const int t = threadIdx.x;
    const int rowBase = b << BSHIFT;
    const int eS = bstart[b];
    const int eE = bstart[b + 1];

    cnt[t] = 0;
    __syncthreads();
    for (int j = eS + t; j < eE; j += 512) {
        unsigned rc = ebuf[j];
        atomicAdd(&cnt[rc >> COLBITS], 1);
    }
    __syncthreads();
    sc[t] = cnt[t];
    __syncthreads();
    for (int o = 1; o < 512; o <<= 1) {       // Hillis-Steele inclusive scan
        int v = (t >= o) ? sc[t - o] : 0;
        __syncthreads();
        sc[t] += v;
        __syncthreads();
    }
    int node = rowBase + t;
    int myCnt = cnt[t];
    if (node < N) {
        offs_end[node] = eS + sc[t];
        inv[node] = rsqrtf((float)myCnt + 1.0f);
    }
    __syncthreads();
    cnt[t] = eS + sc[t] - myCnt;              // exclusive start -> cursor
    __syncthreads();
    for (int j = eS + t; j < eE; j += 512) {
        unsigned rc = ebuf[j];
        int pos = atomicAdd(&cnt[rc >> COLBITS], 1);
        csr[pos] = (int)(rc & ((1u << COLBITS) - 1));
    }
}

// ---- 5. prescale into slice-major: xsl[s][n][16] = fp16(x[n][s*16+c] * inv[n]) ----
__global__ __launch_bounds__(256) void prescale_kernel(const float4* __restrict__ x4,
                                                       const float* __restrict__ inv,
                                                       _Float16* __restrict__ xsl, int N) {
    int i = blockIdx.x * blockDim.x + threadIdx.x;   // one float4 = 4 channels
    int total4 = N * 32;
    if (i >= total4) return;
    int node = i >> 5;
    int c4 = i & 31;
    int slice = c4 >> 2, part = c4 & 3;
    float s = inv[node];
    float4 v = x4[i];
    __half2 h[2];
    h[0] = __floats2half2_rn(v.x * s, v.y * s);
    h[1] = __floats2half2_rn(v.z * s, v.w * s);
    float2* dst = (float2*)(xsl + ((size_t)slice * N + node) * 16 + part * 4);
    *dst = *(const float2*)h;                  // single 8B store
}

// ---- 6. gather (XCD-sliced): block b -> slice b&7, nodes [(b>>3)*128, +128) ----
// 2 lanes per node (16B each). Slice (3.2MB) stays resident in the XCD's L2;
// csr/offs_end streamed with nontemporal loads to avoid evicting it.
__global__ __launch_bounds__(256) void gather_kernel(const _Float16* __restrict__ xsl,
                                                     const int* __restrict__ offs_end,
                                                     const int* __restrict__ csr,
                                                     const float* __restrict__ inv,
                                                     _Float16* __restrict__ aggs, int N) {
    const int b = blockIdx.x;
    const int s = b & (NSLICE - 1);
    const int chunk = b >> 3;
    const int t = threadIdx.x;
    const int ln = t >> 1, h = t & 1;
    const int node = chunk * 128 + ln;
    if (node >= N) return;

    const float4* xp = (const float4*)(xsl + (size_t)s * N * 16);  // 2 float4 per row
    int es = (node == 0) ? 0 : __builtin_nontemporal_load(&offs_end[node - 1]);
    int ee = __builtin_nontemporal_load(&offs_end[node]);

    float a[8];
    {   // self term (already inv-scaled in xsl)
        float4 hv = xp[(size_t)node * 2 + h];
        const __half2* p = (const __half2*)&hv;
#pragma unroll
        for (int q = 0; q < 4; ++q) {
            float2 f = __half22float2(p[q]);
            a[2 * q] = f.x; a[2 * q + 1] = f.y;
        }
    }
    int j = es;
    for (; j + 2 <= ee; j += 2) {
        int c0 = __builtin_nontemporal_load(&csr[j]);
        int c1 = __builtin_nontemporal_load(&csr[j + 1]);
        float4 v0 = xp[(size_t)c0 * 2 + h];
        float4 v1 = xp[(size_t)c1 * 2 + h];
        const __half2* p0 = (const __half2*)&v0;
        const __half2* p1 = (const __half2*)&v1;
#pragma unroll
        for (int q = 0; q < 4; ++q) {
            float2 f = __half22float2(p0[q]);
            a[2 * q] += f.x; a[2 * q + 1] += f.y;
        }
#pragma unroll
        for (int q = 0; q < 4; ++q) {
            float2 f = __half22float2(p1[q]);
            a[2 * q] += f.x; a[2 * q + 1] += f.y;
        }
    }
    if (j < ee) {
        int c = __builtin_nontemporal_load(&csr[j]);
        float4 v = xp[(size_t)c * 2 + h];
        const __half2* p = (const __half2*)&v;
#pragma unroll
        for (int q = 0; q < 4; ++q) {
            float2 f = __half22float2(p[q]);
            a[2 * q] += f.x; a[2 * q + 1] += f.y;
        }
    }
    float invn = inv[node];
    __half2 hh[4];
#pragma unroll
    for (int q = 0; q < 4; ++q)
        hh[q] = __floats2half2_rn(a[2 * q] * invn, a[2 * q + 1] * invn);
    // contiguous per-block write: thread t writes 16B at slice-major row offset
    float4* dst = (float4*)(aggs + ((size_t)s * N + node) * 16 + h * 8);
    *dst = *(const float4*)hh;
}

// ---- 7. W -> fp16 ----
__global__ void wconv_kernel(const float4* __restrict__ W4, __half2* __restrict__ Wh2,
                             int total4) {
    int i = blockIdx.x * blockDim.x + threadIdx.x;
    if (i >= total4) return;
    float4 v = W4[i];
    Wh2[i * 2]     = __floats2half2_rn(v.x, v.y);
    Wh2[i * 2 + 1] = __floats2half2_rn(v.z, v.w);
}

// ---- 8. MFMA GEMM: out[n][o] = sum_k A[n][k] * Wh[o][k]; A slice-major fp16 ----
// mfma_f32_16x16x32_f16; A lane row=l&15, k=(l>>4)*8+i (+kk*32).
// Slice-major: k0=kg*8+kk*32 -> slice=(kg>>1)+2*kk, within=(kg&1)*8.
__global__ __launch_bounds__(256) void mfma_matmul_kernel(const _Float16* __restrict__ A,
                                                          const _Float16* __restrict__ Wh,
                                                          float* __restrict__ out, int N) {
    const int wave = threadIdx.x >> 6;
    const int lane = threadIdx.x & 63;
    const int row0 = blockIdx.x * 64 + wave * 16;
    if (row0 >= N) return;
    const int r = lane & 15;
    const int kg = lane >> 4;
    const int arow = row0 + r;

    v8hf a[4];
    if (arow < N) {
#pragma unroll
        for (int kk = 0; kk < 4; ++kk) {
            int slice = (kg >> 1) + (kk << 1);
            int within = (kg & 1) * 8;
            a[kk] = *(const v8hf*)(A + ((size_t)slice * N + arow) * 16 + within);
        }
    } else {
#pragma unroll
        for (int kk = 0; kk < 4; ++kk)
#pragma unroll
            for (int q = 0; q < 8; ++q) a[kk][q] = (_Float16)0.0f;
    }

#pragma unroll
    for (int t = 0; t < 8; ++t) {
        v4f acc = {0.0f, 0.0f, 0.0f, 0.0f};
        const v8hf* bp = (const v8hf*)(Wh + (size_t)(t * 16 + r) * C + kg * 8);
#pragma unroll
        for (int kk = 0; kk < 4; ++kk)
            acc = __builtin_amdgcn_mfma_f32_16x16x32_f16(a[kk], bp[kk * 4], acc, 0, 0, 0);
#pragma unroll
        for (int reg = 0; reg < 4; ++reg) {
            int rr = row0 + kg * 4 + reg;
            if (rr < N) out[(size_t)rr * C + t * 16 + r] = acc[reg];
        }
    }
}

extern "C" void kernel_launch(void* const* d_in, const int* in_sizes, int n_in,
                              void* d_out, int out_size, void* d_ws, size_t ws_size,
                              hipStream_t stream) {
    const float* x  = (const float*)d_in[0];
    const int*   ei = (const int*)d_in[1];
    const float* W  = (const float*)d_in[2];
    float* out = (float*)d_out;

    const int N = in_sizes[0] / C;
    const int E = in_sizes[1] / 2;
    const int* rowI = ei;        // edge_index[0]
    const int* colI = ei + E;    // edge_index[1]

    const int NB = (N + BWIDTH - 1) / BWIDTH;     // 196 for N=100000

    // workspace carve-up (256B-aligned regions)
    char* ws = (char*)d_ws;
    size_t off = 0;
    auto carve = [&](size_t bytes) -> void* {
        off = (off + 255) & ~(size_t)255;
        void* p = ws + off;
        off += bytes;
        return p;
    };
    int*      bcount   = (int*)carve((size_t)NBMAX * 4);
    int*      bstart   = (int*)carve((size_t)(NBMAX + 1) * 4);
    int*      gcur     = (int*)carve((size_t)NBMAX * 4);
    int*      offs_end = (int*)carve((size_t)N * 4);
    float*    inv      = (float*)carve((size_t)N * 4);
    int*      csr      = (int*)carve((size_t)E * 4);
    _Float16* xsl      = (_Float16*)carve((size_t)N * C * 2);  // slice-major [8][N][16]
    // ebuf (dead after p3_place) and aggs (written by gather) share a region
    unsigned* ebuf;
    _Float16* aggs;
    {
        off = (off + 255) & ~(size_t)255;
        ebuf = (unsigned*)(ws + off);
        aggs = (_Float16*)(ws + off);
        size_t esz = (size_t)E * 4, asz = (size_t)N * C * 2;
        off += (esz > asz ? esz : asz);
    }
    __half2*  Wh = (__half2*)carve((size_t)C * C * 2);

    hipMemsetAsync(bcount, 0, (size_t)NBMAX * 4, stream);

    wconv_kernel<<<(C * C / 4 + 255) / 256, 256, 0, stream>>>((const float4*)W, Wh, C * C / 4);

    int E4 = E >> 2;
    bucket_hist_kernel<<<256, 256, 0, stream>>>((const int4*)rowI, rowI, bcount, E4, E, NB);
    bucket_scan_kernel<<<1, 256, 0, stream>>>(bcount, bstart, gcur, NB);

    int nChunks = (E + 4095) / 4096;
    p2_scatter_kernel<<<nChunks, 256, 0, stream>>>(rowI, colI, gcur, ebuf, E);
    p3_place_kernel<<<NB, 512, 0, stream>>>(ebuf, bstart, offs_end, inv, csr, N);

    int total4 = N * 32;
    prescale_kernel<<<(total4 + 255) / 256, 256, 0, stream>>>((const float4*)x, inv, xsl, N);

    int nChunksG = (N + 127) / 128;
    gather_kernel<<<nChunksG * NSLICE, 256, 0, stream>>>(xsl, offs_end, csr, inv, aggs, N);

    mfma_matmul_kernel<<<(N + 63) / 64, 256, 0, stream>>>(aggs, (const _Float16*)Wh, out, N);
}

// Round 7
// 160.037 us; speedup vs baseline: 1.5977x; 1.5977x over previous
//
#include <hip/hip_runtime.h>
#include <hip/hip_fp16.h>
#include <math.h>

#define C 128
#define BSHIFT 9        // bucket width = 512 nodes
#define BWIDTH 512
#define NBMAX 256       // >= ceil(100000/512)=196
#define COLBITS 17      // N=100000 < 2^17; ebuf packs (lrow<<17)|col
#define P2CHUNK 4096    // edges per p2 block (16/thread)
#define P3CAP 10240     // LDS staging capacity for one bucket (avg 8192, sigma~90)

typedef _Float16 v8hf __attribute__((ext_vector_type(8)));
typedef float v4f __attribute__((ext_vector_type(4)));

// ---- 1. bucket histogram: bcount[row>>9] += 1 (LDS-aggregated) ----
__global__ __launch_bounds__(256) void bucket_hist_kernel(const int4* __restrict__ rowI4,
                                                          const int* __restrict__ rowI,
                                                          int* __restrict__ bcount,
                                                          int E4, int E, int NB) {
    __shared__ int h[NBMAX];
    int t = threadIdx.x;
    h[t] = 0;
    __syncthreads();
    for (int i = blockIdx.x * 256 + t; i < E4; i += gridDim.x * 256) {
        int4 r = rowI4[i];
        atomicAdd(&h[r.x >> BSHIFT], 1);
        atomicAdd(&h[r.y >> BSHIFT], 1);
        atomicAdd(&h[r.z >> BSHIFT], 1);
        atomicAdd(&h[r.w >> BSHIFT], 1);
    }
    if (blockIdx.x == 0 && t == 0) {          // tail (E not multiple of 4)
        for (int e = E4 * 4; e < E; ++e) atomicAdd(&h[rowI[e] >> BSHIFT], 1);
    }
    __syncthreads();
    if (t < NB && h[t]) atomicAdd(&bcount[t], h[t]);
}

// ---- 2. bucket scan: parallel LDS scan (NB <= 256) ----
__global__ __launch_bounds__(256) void bucket_scan_kernel(const int* __restrict__ bcount,
                                                          int* __restrict__ bstart,
                                                          int* __restrict__ gcur, int NB) {
    __shared__ int sc[256];
    int t = threadIdx.x;
    int v = (t < NB) ? bcount[t] : 0;
    sc[t] = v;
    __syncthreads();
    for (int o = 1; o < 256; o <<= 1) {       // Hillis-Steele inclusive
        int u = (t >= o) ? sc[t - o] : 0;
        __syncthreads();
        sc[t] += u;
        __syncthreads();
    }
    int excl = sc[t] - v;
    if (t < NB) { bstart[t] = excl; gcur[t] = excl; }
    if (t == 255) bstart[NB] = sc[255];
}

// ---- 3. scatter edges into bucket-ordered ebuf via LDS sort (coalesced writes) ----
__global__ __launch_bounds__(256) void p2_scatter_kernel(const int* __restrict__ rowI,
                                                         const int* __restrict__ colI,
                                                         int* __restrict__ gcur,
                                                         unsigned* __restrict__ ebuf, int E) {
    __shared__ int cnt[NBMAX];
    __shared__ int sc[NBMAX];                 // scan -> reused as lstart
    __shared__ int delta[NBMAX];              // global base - lstart
    __shared__ unsigned sorted[P2CHUNK];
    __shared__ unsigned char bkt[P2CHUNK];
    const int t = threadIdx.x;
    cnt[t] = 0;
    __syncthreads();
    const int e0 = blockIdx.x * P2CHUNK;
    int ranks[16];
#pragma unroll
    for (int k = 0; k < 16; ++k) {
        int e = e0 + k * 256 + t;
        if (e < E) ranks[k] = atomicAdd(&cnt[rowI[e] >> BSHIFT], 1);
    }
    __syncthreads();
    sc[t] = cnt[t];
    __syncthreads();
    for (int o = 1; o < 256; o <<= 1) {       // Hillis-Steele inclusive
        int v = (t >= o) ? sc[t - o] : 0;
        __syncthreads();
        sc[t] += v;
        __syncthreads();
    }
    {
        int c = cnt[t];
        int ls = sc[t] - c;                   // local exclusive start
        int gb = c ? atomicAdd(&gcur[t], c) : 0;
        delta[t] = gb - ls;
        sc[t] = ls;                           // sc now holds lstart
    }
    __syncthreads();
#pragma unroll
    for (int k = 0; k < 16; ++k) {
        int e = e0 + k * 256 + t;
        if (e < E) {
            int r = rowI[e];                  // L1/L2-hot re-read
            unsigned cc = (unsigned)colI[e];
            int b = r >> BSHIFT;
            int lp = sc[b] + ranks[k];
            sorted[lp] = ((unsigned)(r & (BWIDTH - 1)) << COLBITS) | cc;
            bkt[lp] = (unsigned char)b;
        }
    }
    __syncthreads();
    int total = E - e0; if (total > P2CHUNK) total = P2CHUNK;
#pragma unroll
    for (int k = 0; k < 16; ++k) {            // linear LDS -> coalesced global runs
        int i = k * 256 + t;
        if (i < total) ebuf[delta[bkt[i]] + i] = sorted[i];
    }
}

// ---- 4. per-bucket place via LDS staging; csr written as a linear stream ----
// Emits offs_end[node], inv[node] = rsqrt(deg+1), csr (cols only).
__global__ __launch_bounds__(512) void p3_place_kernel(const unsigned* __restrict__ ebuf,
                                                       const int* __restrict__ bstart,
                                                       int* __restrict__ offs_end,
                                                       float* __restrict__ inv,
                                                       int* __restrict__ csr, int N) {
    __shared__ int cnt[BWIDTH];
    __shared__ int sc[BWIDTH];
    __shared__ int sortedCol[P3CAP];          // 40 KB
    const int b = blockIdx.x;
    const int t = threadIdx.x;
    const int rowBase = b << BSHIFT;
    const int eS = bstart[b];
    const int eE = bstart[b + 1];

    cnt[t] = 0;
    __syncthreads();
    for (int j = eS + t; j < eE; j += 512)
        atomicAdd(&cnt[ebuf[j] >> COLBITS], 1);
    __syncthreads();
    sc[t] = cnt[t];
    __syncthreads();
    for (int o = 1; o < 512; o <<= 1) {       // Hillis-Steele inclusive scan
        int v = (t >= o) ? sc[t - o] : 0;
        __syncthreads();
        sc[t] += v;
        __syncthreads();
    }
    int node = rowBase + t;
    int myCnt = cnt[t];
    if (node < N) {
        offs_end[node] = eS + sc[t];
        inv[node] = rsqrtf((float)myCnt + 1.0f);
    }
    __syncthreads();
    cnt[t] = sc[t] - myCnt;                   // exclusive start -> local cursor
    __syncthreads();
    for (int j = eS + t; j < eE; j += 512) {
        unsigned rc = ebuf[j];                // L2-hot re-read
        int slot = atomicAdd(&cnt[rc >> COLBITS], 1);   // local 0-based slot
        int col = (int)(rc & ((1u << COLBITS) - 1));
        if (slot < P3CAP) sortedCol[slot] = col;
        else csr[eS + slot] = col;            // overflow fallback (rare/none)
    }
    __syncthreads();
    int total = eE - eS; if (total > P3CAP) total = P3CAP;
    for (int i = t; i < total; i += 512)      // pure streaming write
        csr[eS + i] = sortedCol[i];
}

// ---- 5. prescale: xsh[n][c] = fp16(x[n][c] * inv[n]) ----
__global__ __launch_bounds__(256) void prescale_kernel(const float4* __restrict__ x4,
                                                       const float* __restrict__ inv,
                                                       __half2* __restrict__ xsh2, int total4) {
    int i = blockIdx.x * blockDim.x + threadIdx.x;
    if (i >= total4) return;
    int node = i >> 5;                        // 32 float4 per row
    float s = inv[node];
    float4 v = x4[i];
    xsh2[i * 2]     = __floats2half2_rn(v.x * s, v.y * s);
    xsh2[i * 2 + 1] = __floats2half2_rn(v.z * s, v.w * s);
}

// ---- 6. gather: 16 lanes/node (256B rows); fp32 accumulate; unroll 4 ----
#define ACC4(vv)                                                   \
    {                                                              \
        const __half2* p_ = (const __half2*)&(vv);                 \
        _Pragma("unroll")                                          \
        for (int q = 0; q < 4; ++q) {                              \
            float2 f_ = __half22float2(p_[q]);                     \
            a[2 * q] += f_.x; a[2 * q + 1] += f_.y;                \
        }                                                          \
    }

__global__ __launch_bounds__(256) void gather_kernel(const float4* __restrict__ xsh4,
                                                     const int* __restrict__ offs_end,
                                                     const int* __restrict__ csr,
                                                     const float* __restrict__ inv,
                                                     float4* __restrict__ aggh4, int N) {
    int t = blockIdx.x * blockDim.x + threadIdx.x;
    int node = t >> 4;
    if (node >= N) return;
    int lane = t & 15;
    int s = (node == 0) ? 0 : offs_end[node - 1];
    int e = offs_end[node];

    float a[8];
    {   // self term (already inv-scaled in xsh)
        float4 h = xsh4[(size_t)node * 16 + lane];
        const __half2* p = (const __half2*)&h;
#pragma unroll
        for (int q = 0; q < 4; ++q) {
            float2 f = __half22float2(p[q]);
            a[2 * q] = f.x; a[2 * q + 1] = f.y;
        }
    }
    int j = s;
    for (; j + 4 <= e; j += 4) {
        int c0 = csr[j], c1 = csr[j + 1], c2 = csr[j + 2], c3 = csr[j + 3];
        float4 v0 = xsh4[(size_t)c0 * 16 + lane];
        float4 v1 = xsh4[(size_t)c1 * 16 + lane];
        float4 v2 = xsh4[(size_t)c2 * 16 + lane];
        float4 v3 = xsh4[(size_t)c3 * 16 + lane];
        ACC4(v0) ACC4(v1) ACC4(v2) ACC4(v3)
    }
    for (; j < e; ++j) {
        int c = csr[j];
        float4 v = xsh4[(size_t)c * 16 + lane];
        ACC4(v)
    }
    float invn = inv[node];
    __half2 hh[4];
#pragma unroll
    for (int q = 0; q < 4; ++q)
        hh[q] = __floats2half2_rn(a[2 * q] * invn, a[2 * q + 1] * invn);
    aggh4[(size_t)node * 16 + lane] = *(const float4*)hh;
}

// ---- 7. W -> fp16 ----
__global__ void wconv_kernel(const float4* __restrict__ W4, __half2* __restrict__ Wh2,
                             int total4) {
    int i = blockIdx.x * blockDim.x + threadIdx.x;
    if (i >= total4) return;
    float4 v = W4[i];
    Wh2[i * 2]     = __floats2half2_rn(v.x, v.y);
    Wh2[i * 2 + 1] = __floats2half2_rn(v.z, v.w);
}

// ---- 8. MFMA GEMM: out[n][o] = sum_k A[n][k] * Wh[o][k]  (A,Wh fp16, out fp32)
// Block = 256 threads = 4 waves; wave owns 16 rows x 128 cols; no LDS.
// mfma_f32_16x16x32_f16: A lane row=l&15, k=(l>>4)*8+i (+kk*32).
// D: col=lane&15, row=(lane>>4)*4+reg  [m89, dtype-independent].
__global__ __launch_bounds__(256) void mfma_matmul_kernel(const _Float16* __restrict__ A,
                                                          const _Float16* __restrict__ Wh,
                                                          float* __restrict__ out, int N) {
    const int wave = threadIdx.x >> 6;
    const int lane = threadIdx.x & 63;
    const int row0 = blockIdx.x * 64 + wave * 16;
    if (row0 >= N) return;
    const int r = lane & 15;
    const int kg = lane >> 4;

    v8hf a[4];
    const int arow = row0 + r;
    if (arow < N) {
        const v8hf* ap = (const v8hf*)(A + (size_t)arow * C + kg * 8);
#pragma unroll
        for (int kk = 0; kk < 4; ++kk) a[kk] = ap[kk * 4];   // +32 fp16 per step
    } else {
#pragma unroll
        for (int kk = 0; kk < 4; ++kk)
#pragma unroll
            for (int q = 0; q < 8; ++q) a[kk][q] = (_Float16)0.0f;
    }

#pragma unroll
    for (int t = 0; t < 8; ++t) {
        v4f acc = {0.0f, 0.0f, 0.0f, 0.0f};
        const v8hf* bp = (const v8hf*)(Wh + (size_t)(t * 16 + r) * C + kg * 8);
#pragma unroll
        for (int kk = 0; kk < 4; ++kk)
            acc = __builtin_amdgcn_mfma_f32_16x16x32_f16(a[kk], bp[kk * 4], acc, 0, 0, 0);
#pragma unroll
        for (int reg = 0; reg < 4; ++reg) {
            int rr = row0 + kg * 4 + reg;
            if (rr < N) out[(size_t)rr * C + t * 16 + r] = acc[reg];
        }
    }
}

extern "C" void kernel_launch(void* const* d_in, const int* in_sizes, int n_in,
                              void* d_out, int out_size, void* d_ws, size_t ws_size,
                              hipStream_t stream) {
    const float* x  = (const float*)d_in[0];
    const int*   ei = (const int*)d_in[1];
    const float* W  = (const float*)d_in[2];
    float* out = (float*)d_out;

    const int N = in_sizes[0] / C;
    const int E = in_sizes[1] / 2;
    const int* rowI = ei;        // edge_index[0]
    const int* colI = ei + E;    // edge_index[1]

    const int NB = (N + BWIDTH - 1) / BWIDTH;     // 196 for N=100000

    // workspace carve-up (256B-aligned regions)
    char* ws = (char*)d_ws;
    size_t off = 0;
    auto carve = [&](size_t bytes) -> void* {
        off = (off + 255) & ~(size_t)255;
        void* p = ws + off;
        off += bytes;
        return p;
    };
    int*      bcount   = (int*)carve((size_t)NBMAX * 4);
    int*      bstart   = (int*)carve((size_t)(NBMAX + 1) * 4);
    int*      gcur     = (int*)carve((size_t)NBMAX * 4);
    int*      offs_end = (int*)carve((size_t)N * 4);
    float*    inv      = (float*)carve((size_t)N * 4);
    int*      csr      = (int*)carve((size_t)E * 4);
    __half2*  xsh      = (__half2*)carve((size_t)N * C * 2);
    // ebuf (dead after p3_place) and aggh (written by gather) share a region
    unsigned* ebuf;
    _Float16* aggh;
    {
        off = (off + 255) & ~(size_t)255;
        ebuf = (unsigned*)(ws + off);
        aggh = (_Float16*)(ws + off);
        size_t esz = (size_t)E * 4, asz = (size_t)N * C * 2;
        off += (esz > asz ? esz : asz);
    }
    __half2*  Wh = (__half2*)carve((size_t)C * C * 2);

    hipMemsetAsync(bcount, 0, (size_t)NBMAX * 4, stream);

    wconv_kernel<<<(C * C / 4 + 255) / 256, 256, 0, stream>>>((const float4*)W, Wh, C * C / 4);

    int E4 = E >> 2;
    bucket_hist_kernel<<<256, 256, 0, stream>>>((const int4*)rowI, rowI, bcount, E4, E, NB);
    bucket_scan_kernel<<<1, 256, 0, stream>>>(bcount, bstart, gcur, NB);

    int nChunks = (E + P2CHUNK - 1) / P2CHUNK;
    p2_scatter_kernel<<<nChunks, 256, 0, stream>>>(rowI, colI, gcur, ebuf, E);
    p3_place_kernel<<<NB, 512, 0, stream>>>(ebuf, bstart, offs_end, inv, csr, N);

    int total4 = N * 32;
    prescale_kernel<<<(total4 + 255) / 256, 256, 0, stream>>>((const float4*)x, inv, xsh,
                                                              total4);

    long long gt = (long long)N * 16;
    gather_kernel<<<(int)((gt + 255) / 256), 256, 0, stream>>>((const float4*)xsh, offs_end,
                                                               csr, inv, (float4*)aggh, N);

    mfma_matmul_kernel<<<(N + 63) / 64, 256, 0, stream>>>(aggh, (const _Float16*)Wh, out, N);
}

// Round 8
// 144.393 us; speedup vs baseline: 1.7708x; 1.1083x over previous
//
#include <hip/hip_runtime.h>
#include <hip/hip_fp16.h>
#include <math.h>

#define C 128
#define BSHIFT 9        // bucket width = 512 nodes
#define BWIDTH 512
#define NBMAX 256       // >= ceil(100000/512)=196
#define COLBITS 17      // N=100000 < 2^17; ebuf packs (lrow<<17)|col
#define P2CHUNK 4096    // edges per p2 block (16/thread)
#define P3CAP 10240     // LDS staging capacity for one bucket (avg 8192)
#define APITCH 136      // fp16 pitch for LDS agg tile: 272B rows -> 2-way conflicts (free)

typedef _Float16 v8hf __attribute__((ext_vector_type(8)));
typedef float v4f __attribute__((ext_vector_type(4)));

// ---- 1. bucket histogram: bcount[row>>9] += 1 (LDS-aggregated) ----
__global__ __launch_bounds__(256) void bucket_hist_kernel(const int4* __restrict__ rowI4,
                                                          const int* __restrict__ rowI,
                                                          int* __restrict__ bcount,
                                                          int E4, int E, int NB) {
    __shared__ int h[NBMAX];
    int t = threadIdx.x;
    h[t] = 0;
    __syncthreads();
    for (int i = blockIdx.x * 256 + t; i < E4; i += gridDim.x * 256) {
        int4 r = rowI4[i];
        atomicAdd(&h[r.x >> BSHIFT], 1);
        atomicAdd(&h[r.y >> BSHIFT], 1);
        atomicAdd(&h[r.z >> BSHIFT], 1);
        atomicAdd(&h[r.w >> BSHIFT], 1);
    }
    if (blockIdx.x == 0 && t == 0) {          // tail (E not multiple of 4)
        for (int e = E4 * 4; e < E; ++e) atomicAdd(&h[rowI[e] >> BSHIFT], 1);
    }
    __syncthreads();
    if (t < NB && h[t]) atomicAdd(&bcount[t], h[t]);
}

// ---- 2. bucket scan: parallel LDS scan (NB <= 256) ----
__global__ __launch_bounds__(256) void bucket_scan_kernel(const int* __restrict__ bcount,
                                                          int* __restrict__ bstart,
                                                          int* __restrict__ gcur, int NB) {
    __shared__ int sc[256];
    int t = threadIdx.x;
    int v = (t < NB) ? bcount[t] : 0;
    sc[t] = v;
    __syncthreads();
    for (int o = 1; o < 256; o <<= 1) {       // Hillis-Steele inclusive
        int u = (t >= o) ? sc[t - o] : 0;
        __syncthreads();
        sc[t] += u;
        __syncthreads();
    }
    int excl = sc[t] - v;
    if (t < NB) { bstart[t] = excl; gcur[t] = excl; }
    if (t == 255) bstart[NB] = sc[255];
}

// ---- 3. scatter edges into bucket-ordered ebuf via LDS sort (coalesced writes) ----
__global__ __launch_bounds__(256) void p2_scatter_kernel(const int* __restrict__ rowI,
                                                         const int* __restrict__ colI,
                                                         int* __restrict__ gcur,
                                                         unsigned* __restrict__ ebuf, int E) {
    __shared__ int cnt[NBMAX];
    __shared__ int sc[NBMAX];                 // scan -> reused as lstart
    __shared__ int delta[NBMAX];              // global base - lstart
    __shared__ unsigned sorted[P2CHUNK];
    __shared__ unsigned char bkt[P2CHUNK];
    const int t = threadIdx.x;
    cnt[t] = 0;
    __syncthreads();
    const int e0 = blockIdx.x * P2CHUNK;
    int ranks[16];
#pragma unroll
    for (int k = 0; k < 16; ++k) {
        int e = e0 + k * 256 + t;
        if (e < E) ranks[k] = atomicAdd(&cnt[rowI[e] >> BSHIFT], 1);
    }
    __syncthreads();
    sc[t] = cnt[t];
    __syncthreads();
    for (int o = 1; o < 256; o <<= 1) {       // Hillis-Steele inclusive
        int v = (t >= o) ? sc[t - o] : 0;
        __syncthreads();
        sc[t] += v;
        __syncthreads();
    }
    {
        int c = cnt[t];
        int ls = sc[t] - c;                   // local exclusive start
        int gb = c ? atomicAdd(&gcur[t], c) : 0;
        delta[t] = gb - ls;
        sc[t] = ls;                           // sc now holds lstart
    }
    __syncthreads();
#pragma unroll
    for (int k = 0; k < 16; ++k) {
        int e = e0 + k * 256 + t;
        if (e < E) {
            int r = rowI[e];                  // L1/L2-hot re-read
            unsigned cc = (unsigned)colI[e];
            int b = r >> BSHIFT;
            int lp = sc[b] + ranks[k];
            sorted[lp] = ((unsigned)(r & (BWIDTH - 1)) << COLBITS) | cc;
            bkt[lp] = (unsigned char)b;
        }
    }
    __syncthreads();
    int total = E - e0; if (total > P2CHUNK) total = P2CHUNK;
#pragma unroll
    for (int k = 0; k < 16; ++k) {            // linear LDS -> coalesced global runs
        int i = k * 256 + t;
        if (i < total) ebuf[delta[bkt[i]] + i] = sorted[i];
    }
}

// ---- 4. per-bucket place via LDS staging; csr written as a linear stream ----
// Emits offs_end[node], inv[node] = rsqrt(deg+1), csr (cols only).
__global__ __launch_bounds__(512) void p3_place_kernel(const unsigned* __restrict__ ebuf,
                                                       const int* __restrict__ bstart,
                                                       int* __restrict__ offs_end,
                                                       float* __restrict__ inv,
                                                       int* __restrict__ csr, int N) {
    __shared__ int cnt[BWIDTH];
    __shared__ int sc[BWIDTH];
    __shared__ int sortedCol[P3CAP];          // 40 KB
    const int b = blockIdx.x;
    const int t = threadIdx.x;
    const int rowBase = b << BSHIFT;
    const int eS = bstart[b];
    const int eE = bstart[b + 1];

    cnt[t] = 0;
    __syncthreads();
    for (int j = eS + t; j < eE; j += 512)
        atomicAdd(&cnt[ebuf[j] >> COLBITS], 1);
    __syncthreads();
    sc[t] = cnt[t];
    __syncthreads();
    for (int o = 1; o < 512; o <<= 1) {       // Hillis-Steele inclusive scan
        int v = (t >= o) ? sc[t - o] : 0;
        __syncthreads();
        sc[t] += v;
        __syncthreads();
    }
    int node = rowBase + t;
    int myCnt = cnt[t];
    if (node < N) {
        offs_end[node] = eS + sc[t];
        inv[node] = rsqrtf((float)myCnt + 1.0f);
    }
    __syncthreads();
    cnt[t] = sc[t] - myCnt;                   // exclusive start -> local cursor
    __syncthreads();
    for (int j = eS + t; j < eE; j += 512) {
        unsigned rc = ebuf[j];                // L2-hot re-read
        int slot = atomicAdd(&cnt[rc >> COLBITS], 1);   // local 0-based slot
        int col = (int)(rc & ((1u << COLBITS) - 1));
        if (slot < P3CAP) sortedCol[slot] = col;
        else csr[eS + slot] = col;            // overflow fallback (rare/none)
    }
    __syncthreads();
    int total = eE - eS; if (total > P3CAP) total = P3CAP;
    for (int i = t; i < total; i += 512)      // pure streaming write
        csr[eS + i] = sortedCol[i];
}

// ---- 5. prescale: xsh[n][c] = fp16(x[n][c] * inv[n]) ----
__global__ __launch_bounds__(256) void prescale_kernel(const float4* __restrict__ x4,
                                                       const float* __restrict__ inv,
                                                       __half2* __restrict__ xsh2, int total4) {
    int i = blockIdx.x * blockDim.x + threadIdx.x;
    if (i >= total4) return;
    int node = i >> 5;                        // 32 float4 per row
    float s = inv[node];
    float4 v = x4[i];
    xsh2[i * 2]     = __floats2half2_rn(v.x * s, v.y * s);
    xsh2[i * 2 + 1] = __floats2half2_rn(v.z * s, v.w * s);
}

// ---- 6. W -> fp16 ----
__global__ void wconv_kernel(const float4* __restrict__ W4, __half2* __restrict__ Wh2,
                             int total4) {
    int i = blockIdx.x * blockDim.x + threadIdx.x;
    if (i >= total4) return;
    float4 v = W4[i];
    Wh2[i * 2]     = __floats2half2_rn(v.x, v.y);
    Wh2[i * 2 + 1] = __floats2half2_rn(v.z, v.w);
}

// ---- 7. fused gather + MFMA GEMM ----
// Block = 256 threads = 16 nodes x 16 lanes. Phase 1: gather agg rows (fp32 acc,
// fp16 result x inv[dest]) into LDS tile agg[16][APITCH]. Phase 2: 4 waves
// compute out[16 rows][128 cols] = agg @ Wh^T via mfma_f32_16x16x32_f16.
// A lane: row=l&15, k=(l>>4)*8+i (+kk*32); D: col=lane&15, row=(lane>>4)*4+reg.
#define ACC4(vv)                                                   \
    {                                                              \
        const __half2* p_ = (const __half2*)&(vv);                 \
        _Pragma("unroll")                                          \
        for (int q = 0; q < 4; ++q) {                              \
            float2 f_ = __half22float2(p_[q]);                     \
            a[2 * q] += f_.x; a[2 * q + 1] += f_.y;                \
        }                                                          \
    }

__global__ __launch_bounds__(256) void gather_mm_kernel(const float4* __restrict__ xsh4,
                                                        const int* __restrict__ offs_end,
                                                        const int* __restrict__ csr,
                                                        const float* __restrict__ inv,
                                                        const _Float16* __restrict__ Wh,
                                                        float* __restrict__ out, int N) {
    __shared__ _Float16 agg[16][APITCH];      // 4.25 KB
    const int tid = threadIdx.x;
    const int base = blockIdx.x * 16;
    const int r = tid >> 4;                   // block-local node 0..15
    const int c16 = tid & 15;                 // 16B chunk within row
    const int node = base + r;

    float a[8] = {0, 0, 0, 0, 0, 0, 0, 0};
    if (node < N) {
        int s = (node == 0) ? 0 : offs_end[node - 1];
        int e = offs_end[node];
        {   // self term (already inv-scaled in xsh)
            float4 h = xsh4[(size_t)node * 16 + c16];
            const __half2* p = (const __half2*)&h;
#pragma unroll
            for (int q = 0; q < 4; ++q) {
                float2 f = __half22float2(p[q]);
                a[2 * q] = f.x; a[2 * q + 1] = f.y;
            }
        }
        int j = s;
        for (; j + 4 <= e; j += 4) {
            int c0 = csr[j], c1 = csr[j + 1], c2 = csr[j + 2], c3 = csr[j + 3];
            float4 v0 = xsh4[(size_t)c0 * 16 + c16];
            float4 v1 = xsh4[(size_t)c1 * 16 + c16];
            float4 v2 = xsh4[(size_t)c2 * 16 + c16];
            float4 v3 = xsh4[(size_t)c3 * 16 + c16];
            ACC4(v0) ACC4(v1) ACC4(v2) ACC4(v3)
        }
        for (; j < e; ++j) {
            int c = csr[j];
            float4 v = xsh4[(size_t)c * 16 + c16];
            ACC4(v)
        }
        float invn = inv[node];
#pragma unroll
        for (int q = 0; q < 8; ++q) a[q] *= invn;
    }
    {
        __half2 hh[4];
#pragma unroll
        for (int q = 0; q < 4; ++q) hh[q] = __floats2half2_rn(a[2 * q], a[2 * q + 1]);
        *(float4*)&agg[r][c16 * 8] = *(const float4*)hh;   // 16B, 2-way banks (free)
    }
    __syncthreads();

    // ---- MFMA phase: wave w computes col-tiles t = 2w, 2w+1 ----
    const int wave = tid >> 6;
    const int lane = tid & 63;
    const int rr = lane & 15;
    const int kg = lane >> 4;

    v8hf av[4];
#pragma unroll
    for (int kk = 0; kk < 4; ++kk)
        av[kk] = *(const v8hf*)&agg[rr][kg * 8 + kk * 32];

#pragma unroll
    for (int ti = 0; ti < 2; ++ti) {
        const int t = wave * 2 + ti;
        v4f acc = {0.0f, 0.0f, 0.0f, 0.0f};
        const v8hf* bp = (const v8hf*)(Wh + (size_t)(t * 16 + rr) * C + kg * 8);
#pragma unroll
        for (int kk = 0; kk < 4; ++kk)
            acc = __builtin_amdgcn_mfma_f32_16x16x32_f16(av[kk], bp[kk * 4], acc, 0, 0, 0);
#pragma unroll
        for (int reg = 0; reg < 4; ++reg) {
            int orow = base + kg * 4 + reg;
            if (orow < N) out[(size_t)orow * C + t * 16 + rr] = acc[reg];
        }
    }
}

extern "C" void kernel_launch(void* const* d_in, const int* in_sizes, int n_in,
                              void* d_out, int out_size, void* d_ws, size_t ws_size,
                              hipStream_t stream) {
    const float* x  = (const float*)d_in[0];
    const int*   ei = (const int*)d_in[1];
    const float* W  = (const float*)d_in[2];
    float* out = (float*)d_out;

    const int N = in_sizes[0] / C;
    const int E = in_sizes[1] / 2;
    const int* rowI = ei;        // edge_index[0]
    const int* colI = ei + E;    // edge_index[1]

    const int NB = (N + BWIDTH - 1) / BWIDTH;     // 196 for N=100000

    // workspace carve-up (256B-aligned regions)
    char* ws = (char*)d_ws;
    size_t off = 0;
    auto carve = [&](size_t bytes) -> void* {
        off = (off + 255) & ~(size_t)255;
        void* p = ws + off;
        off += bytes;
        return p;
    };
    int*      bcount   = (int*)carve((size_t)NBMAX * 4);
    int*      bstart   = (int*)carve((size_t)(NBMAX + 1) * 4);
    int*      gcur     = (int*)carve((size_t)NBMAX * 4);
    int*      offs_end = (int*)carve((size_t)N * 4);
    float*    inv      = (float*)carve((size_t)N * 4);
    int*      csr      = (int*)carve((size_t)E * 4);
    __half2*  xsh      = (__half2*)carve((size_t)N * C * 2);
    unsigned* ebuf     = (unsigned*)carve((size_t)E * 4);
    __half2*  Wh       = (__half2*)carve((size_t)C * C * 2);

    hipMemsetAsync(bcount, 0, (size_t)NBMAX * 4, stream);

    wconv_kernel<<<(C * C / 4 + 255) / 256, 256, 0, stream>>>((const float4*)W, Wh, C * C / 4);

    int E4 = E >> 2;
    bucket_hist_kernel<<<256, 256, 0, stream>>>((const int4*)rowI, rowI, bcount, E4, E, NB);
    bucket_scan_kernel<<<1, 256, 0, stream>>>(bcount, bstart, gcur, NB);

    int nChunks = (E + P2CHUNK - 1) / P2CHUNK;
    p2_scatter_kernel<<<nChunks, 256, 0, stream>>>(rowI, colI, gcur, ebuf, E);
    p3_place_kernel<<<NB, 512, 0, stream>>>(ebuf, bstart, offs_end, inv, csr, N);

    int total4 = N * 32;
    prescale_kernel<<<(total4 + 255) / 256, 256, 0, stream>>>((const float4*)x, inv, xsh,
                                                              total4);

    gather_mm_kernel<<<(N + 15) / 16, 256, 0, stream>>>((const float4*)xsh, offs_end, csr,
                                                        inv, (const _Float16*)Wh, out, N);
}